// Round 1
// baseline (12177.747 us; speedup 1.0000x reference)
//
#include <hip/hip_runtime.h>

#define N_USERS 100000
#define N_ITEMS 50000
#define N_NODES 150000
#define EMB 64
#define NNZ_TOT 4800000
#define BATCH_SZ 4096

// ---------------- init: acc = ego0 = concat(user,item); ego1 = 0 ----------------
__global__ void lgcn_init(const float* __restrict__ user_emb,
                          const float* __restrict__ item_emb,
                          float* __restrict__ acc,
                          float* __restrict__ ego0,
                          float* __restrict__ ego1) {
    size_t i = (size_t)blockIdx.x * blockDim.x + threadIdx.x;   // float4 index
    const size_t n4 = (size_t)N_NODES * EMB / 4;
    if (i >= n4) return;
    const size_t u4 = (size_t)N_USERS * EMB / 4;
    float4 v;
    if (i < u4) v = ((const float4*)user_emb)[i];
    else        v = ((const float4*)item_emb)[i - u4];
    ((float4*)acc)[i]  = v;
    ((float4*)ego0)[i] = v;
    float4 z; z.x = 0.f; z.y = 0.f; z.z = 0.f; z.w = 0.f;
    ((float4*)ego1)[i] = z;
}

// ---------------- scatter: nxt[row] += val * cur[col], 16 lanes/edge ----------------
__global__ void lgcn_scatter(const int* __restrict__ erow,
                             const int* __restrict__ ecol,
                             const float* __restrict__ eval_,
                             const float* __restrict__ cur,
                             float* __restrict__ nxt) {
    size_t t = (size_t)blockIdx.x * blockDim.x + threadIdx.x;
    size_t e = t >> 4;
    int sub = (int)(t & 15);
    if (e >= (size_t)NNZ_TOT) return;
    int   row = erow[e];
    int   col = ecol[e];
    float v   = eval_[e];
    float4 x = ((const float4*)(cur + (size_t)col * EMB))[sub];
    float* dst = nxt + (size_t)row * EMB + sub * 4;
    atomicAdd(dst + 0, v * x.x);
    atomicAdd(dst + 1, v * x.y);
    atomicAdd(dst + 2, v * x.z);
    atomicAdd(dst + 3, v * x.w);
}

// ---------------- acc += nxt; zero old buffer for reuse ----------------
__global__ void lgcn_add_zero(float* __restrict__ acc,
                              const float* __restrict__ nxt,
                              float* __restrict__ old_) {
    size_t i = (size_t)blockIdx.x * blockDim.x + threadIdx.x;   // float4 index
    const size_t n4 = (size_t)N_NODES * EMB / 4;
    if (i >= n4) return;
    float4 a = ((const float4*)acc)[i];
    float4 b = ((const float4*)nxt)[i];
    a.x += b.x; a.y += b.y; a.z += b.z; a.w += b.w;
    ((float4*)acc)[i] = a;
    float4 z; z.x = 0.f; z.y = 0.f; z.z = 0.f; z.w = 0.f;
    ((float4*)old_)[i] = z;
}

// ---------------- gather: out rows = acc[idx] * 0.25 ----------------
__global__ void lgcn_gather(const float* __restrict__ acc,
                            const int* __restrict__ users,
                            const int* __restrict__ pos,
                            const int* __restrict__ neg,
                            float* __restrict__ out) {
    size_t t = (size_t)blockIdx.x * blockDim.x + threadIdx.x;
    size_t r = t >> 4;
    int sub = (int)(t & 15);
    if (r >= (size_t)(3 * BATCH_SZ)) return;
    int which = (int)(r / BATCH_SZ);
    int b     = (int)(r % BATCH_SZ);
    int node;
    if (which == 0)      node = users[b];
    else if (which == 1) node = N_USERS + pos[b];
    else                 node = N_USERS + neg[b];
    float4 v = ((const float4*)(acc + (size_t)node * EMB))[sub];
    v.x *= 0.25f; v.y *= 0.25f; v.z *= 0.25f; v.w *= 0.25f;
    ((float4*)(out + r * EMB))[sub] = v;
}

extern "C" void kernel_launch(void* const* d_in, const int* in_sizes, int n_in,
                              void* d_out, int out_size, void* d_ws, size_t ws_size,
                              hipStream_t stream) {
    const int*   erow     = (const int*)  d_in[0];
    const int*   ecol     = (const int*)  d_in[1];
    const float* eval_    = (const float*)d_in[2];
    const float* user_emb = (const float*)d_in[3];
    const float* item_emb = (const float*)d_in[4];
    const int*   users    = (const int*)  d_in[5];
    const int*   pos      = (const int*)  d_in[6];
    const int*   neg      = (const int*)  d_in[7];
    float* out = (float*)d_out;

    const size_t tbl_bytes = (size_t)N_NODES * EMB * sizeof(float);   // 38.4 MB
    char* ws = (char*)d_ws;
    float* acc  = (float*)(ws);
    float* ego0 = (float*)(ws + tbl_bytes);
    float* ego1 = (float*)(ws + 2 * tbl_bytes);

    const int blk = 256;
    const size_t n4 = (size_t)N_NODES * EMB / 4;                      // 2.4M
    const int grid_tbl = (int)((n4 + blk - 1) / blk);

    lgcn_init<<<grid_tbl, blk, 0, stream>>>(user_emb, item_emb, acc, ego0, ego1);

    const size_t scatter_threads = (size_t)NNZ_TOT * 16;
    const int grid_scatter = (int)((scatter_threads + blk - 1) / blk);

    float* cur = ego0;
    float* nxt = ego1;
    for (int layer = 0; layer < 3; ++layer) {
        lgcn_scatter<<<grid_scatter, blk, 0, stream>>>(erow, ecol, eval_, cur, nxt);
        // acc += nxt; zero cur (it becomes the scatter target next layer)
        lgcn_add_zero<<<grid_tbl, blk, 0, stream>>>(acc, nxt, cur);
        float* tmp = cur; cur = nxt; nxt = tmp;
    }

    const size_t gth = (size_t)3 * BATCH_SZ * 16;
    const int grid_g = (int)((gth + blk - 1) / blk);
    lgcn_gather<<<grid_g, blk, 0, stream>>>(acc, users, pos, neg, out);
}

// Round 2
// 1412.302 us; speedup vs baseline: 8.6226x; 8.6226x over previous
//
#include <hip/hip_runtime.h>

#define N_USERS 100000
#define N_ITEMS 50000
#define N_NODES 150000
#define EMB 64
#define NNZ_TOT 4800000
#define BATCH_SZ 4096
#define SCAN_N (N_NODES + 1)

// ---------------- ego0 = concat(user, item) ----------------
__global__ void k_init(const float* __restrict__ user_emb,
                       const float* __restrict__ item_emb,
                       float* __restrict__ ego0) {
    size_t i = (size_t)blockIdx.x * blockDim.x + threadIdx.x;   // float4 index
    const size_t n4 = (size_t)N_NODES * EMB / 4;
    if (i >= n4) return;
    const size_t u4 = (size_t)N_USERS * EMB / 4;
    float4 v;
    if (i < u4) v = ((const float4*)user_emb)[i];
    else        v = ((const float4*)item_emb)[i - u4];
    ((float4*)ego0)[i] = v;
}

// ---------------- zero deg + fill counters ----------------
__global__ void k_zero(int* __restrict__ p, int n) {
    int i = blockIdx.x * blockDim.x + threadIdx.x;
    if (i < n) p[i] = 0;
}

// ---------------- histogram of destination rows ----------------
__global__ void k_hist(const int* __restrict__ erow, int* __restrict__ deg) {
    int e = blockIdx.x * blockDim.x + threadIdx.x;
    if (e >= NNZ_TOT) return;
    atomicAdd(&deg[erow[e]], 1);
}

// ---------------- single-block exclusive scan: rowptr[0..N_NODES] ----------------
__global__ __launch_bounds__(1024) void k_scan(const int* __restrict__ deg,
                                               int* __restrict__ rowptr) {
    __shared__ int lds[1024];
    __shared__ int carry_s;
    const int tid = threadIdx.x;
    if (tid == 0) carry_s = 0;
    __syncthreads();
    for (int base = 0; base < SCAN_N; base += 1024 * 8) {
        int vals[8];
        int local = 0;
        #pragma unroll
        for (int j = 0; j < 8; ++j) {
            int idx = base + tid * 8 + j;
            int v = (idx < N_NODES) ? deg[idx] : 0;
            vals[j] = local;            // exclusive within thread
            local += v;
        }
        lds[tid] = local;
        __syncthreads();
        // Hillis-Steele inclusive scan over 1024 thread-sums
        for (int off = 1; off < 1024; off <<= 1) {
            int t = (tid >= off) ? lds[tid - off] : 0;
            __syncthreads();
            lds[tid] += t;
            __syncthreads();
        }
        int thread_excl = lds[tid] - local;
        int carry = carry_s;
        int total = lds[1023];
        #pragma unroll
        for (int j = 0; j < 8; ++j) {
            int idx = base + tid * 8 + j;
            if (idx < SCAN_N) rowptr[idx] = carry + thread_excl + vals[j];
        }
        __syncthreads();
        if (tid == 0) carry_s = carry + total;
        __syncthreads();
    }
}

// ---------------- fill sorted (col,val) pairs ----------------
__global__ void k_fill(const int* __restrict__ erow,
                       const int* __restrict__ ecol,
                       const float* __restrict__ eval_,
                       const int* __restrict__ rowptr,
                       int* __restrict__ fill,
                       int2* __restrict__ pairs) {
    int e = blockIdx.x * blockDim.x + threadIdx.x;
    if (e >= NNZ_TOT) return;
    int r = erow[e];
    int pos = atomicAdd(&fill[r], 1);
    int idx = rowptr[r] + pos;
    int2 p;
    p.x = ecol[e];
    p.y = __float_as_int(eval_[e]);
    pairs[idx] = p;
}

// ---------------- SpMV: one wave per row, lane = emb element ----------------
__global__ void k_spmv(const int* __restrict__ rowptr,
                       const int2* __restrict__ pairs,
                       const float* __restrict__ cur,
                       float* __restrict__ nxt) {
    size_t gid = (size_t)blockIdx.x * blockDim.x + threadIdx.x;
    int row  = (int)(gid >> 6);
    int lane = (int)(gid & 63);
    if (row >= N_NODES) return;
    int start = rowptr[row];
    int end   = rowptr[row + 1];
    float a0 = 0.f, a1 = 0.f;
    int e = start;
    for (; e + 1 < end; e += 2) {
        int2 p0 = pairs[e];
        int2 p1 = pairs[e + 1];
        a0 += __int_as_float(p0.y) * cur[(size_t)p0.x * EMB + lane];
        a1 += __int_as_float(p1.y) * cur[(size_t)p1.x * EMB + lane];
    }
    if (e < end) {
        int2 p = pairs[e];
        a0 += __int_as_float(p.y) * cur[(size_t)p.x * EMB + lane];
    }
    nxt[(size_t)row * EMB + lane] = a0 + a1;
}

// ---------------- out accumulate: out (+)= ego[idx], optional final scale ----------------
__global__ void k_outacc(const float* __restrict__ ego,
                         const int* __restrict__ users,
                         const int* __restrict__ pos,
                         const int* __restrict__ neg,
                         float* __restrict__ out,
                         int accumulate, float scale) {
    size_t t = (size_t)blockIdx.x * blockDim.x + threadIdx.x;
    size_t r = t >> 4;
    int sub = (int)(t & 15);
    if (r >= (size_t)(3 * BATCH_SZ)) return;
    int which = (int)(r / BATCH_SZ);
    int b     = (int)(r % BATCH_SZ);
    int node;
    if (which == 0)      node = users[b];
    else if (which == 1) node = N_USERS + pos[b];
    else                 node = N_USERS + neg[b];
    float4 v = ((const float4*)(ego + (size_t)node * EMB))[sub];
    float4* op = (float4*)(out + r * EMB) + sub;
    if (accumulate) {
        float4 o = *op;
        v.x += o.x; v.y += o.y; v.z += o.z; v.w += o.w;
    }
    v.x *= scale; v.y *= scale; v.z *= scale; v.w *= scale;
    *op = v;
}

extern "C" void kernel_launch(void* const* d_in, const int* in_sizes, int n_in,
                              void* d_out, int out_size, void* d_ws, size_t ws_size,
                              hipStream_t stream) {
    const int*   erow     = (const int*)  d_in[0];
    const int*   ecol     = (const int*)  d_in[1];
    const float* eval_    = (const float*)d_in[2];
    const float* user_emb = (const float*)d_in[3];
    const float* item_emb = (const float*)d_in[4];
    const int*   users    = (const int*)  d_in[5];
    const int*   pos      = (const int*)  d_in[6];
    const int*   neg      = (const int*)  d_in[7];
    float* out = (float*)d_out;

    const size_t tbl_bytes  = (size_t)N_NODES * EMB * sizeof(float);   // 38.4 MB
    const size_t pair_bytes = (size_t)NNZ_TOT * sizeof(int2);          // 38.4 MB
    char* ws = (char*)d_ws;
    float* ego0   = (float*)(ws);
    float* ego1   = (float*)(ws + tbl_bytes);
    int2*  pairs  = (int2*) (ws + 2 * tbl_bytes);
    int*   rowptr = (int*)  (ws + 2 * tbl_bytes + pair_bytes);
    int*   deg    = rowptr + ((SCAN_N + 63) & ~63);
    int*   fill   = deg + N_NODES;

    const int blk = 256;

    // ego0 = concat(user, item)
    const size_t n4 = (size_t)N_NODES * EMB / 4;
    k_init<<<(int)((n4 + blk - 1) / blk), blk, 0, stream>>>(user_emb, item_emb, ego0);

    // CSR build
    k_zero<<<(2 * N_NODES + blk - 1) / blk, blk, 0, stream>>>(deg, 2 * N_NODES); // deg + fill contiguous
    k_hist<<<(NNZ_TOT + blk - 1) / blk, blk, 0, stream>>>(erow, deg);
    k_scan<<<1, 1024, 0, stream>>>(deg, rowptr);
    k_fill<<<(NNZ_TOT + blk - 1) / blk, blk, 0, stream>>>(erow, ecol, eval_, rowptr, fill, pairs);

    // out = ego0[idx]
    const size_t gth = (size_t)3 * BATCH_SZ * 16;
    const int grid_g = (int)((gth + blk - 1) / blk);
    k_outacc<<<grid_g, blk, 0, stream>>>(ego0, users, pos, neg, out, 0, 1.0f);

    // 3 propagation layers
    const size_t spmv_threads = (size_t)N_NODES * 64;
    const int grid_spmv = (int)((spmv_threads + blk - 1) / blk);
    float* cur = ego0;
    float* nxt = ego1;
    for (int layer = 0; layer < 3; ++layer) {
        k_spmv<<<grid_spmv, blk, 0, stream>>>(rowptr, pairs, cur, nxt);
        float scale = (layer == 2) ? 0.25f : 1.0f;
        k_outacc<<<grid_g, blk, 0, stream>>>(nxt, users, pos, neg, out, 1, scale);
        float* tmp = cur; cur = nxt; nxt = tmp;
    }
}